// Round 16
// baseline (57.226 us; speedup 1.0000x reference)
//
#include <hip/hip_runtime.h>

#define B_SZ 8192

// xls row map (per 32-col block): 0-255 x; 256-257 out0; 258-261 out1;
// 262-269 out2; 270-285 out3; 286-317 out4.

// ---------------- masks + unified COMPACTED params ----------
struct MaskArgs {
  const float* fm[6];
  const float* cp[6];
  const float* lr[6];
  float* out_masks;  // d_out base
  float4* cprm;      // compacted params {c10, ml0/8, ml1/8, fidx(xls row)}
  int* cnt;          // active count per stump (global stump idx)
  float* cstf;       // per-output 0.5*sum(ml)
};

__device__ __forceinline__ float wave_max(float v) {
#pragma unroll
  for (int o = 32; o > 0; o >>= 1) v = fmaxf(v, __shfl_xor(v, o));
  return v;
}
__device__ __forceinline__ float wave_sum(float v) {
#pragma unroll
  for (int o = 32; o > 0; o >>= 1) v += __shfl_xor(v, o);
  return v;
}

__global__ __launch_bounds__(64) void ndt_masks(MaskArgs a) {
  const int maskOff[6] = {524288, 524544, 525060, 526100, 528212, 532564};
  const int prmOff[6]  = {0, 256, 772, 1812, 3924, 8276};
  const int cstOff[6]  = {0, 1, 3, 7, 15, 31};
  const int exBase[6]  = {0, 256, 258, 262, 270, 286};  // xls row of extra f=256
  int bid = blockIdx.x, lane = threadIdx.x;
  int d = 0, s = bid, n = 1;
  while (s >= n) { s -= n; n <<= 1; ++d; }   // level d, stump s, n = 2^d
  int Fd = 256 + ((d > 0) ? n : 0);

  const float* fm = a.fm[d] + (size_t)s * Fd;
  float y[5];
#pragma unroll
  for (int j = 0; j < 5; ++j) {
    int f = lane + 64 * j;
    y[j] = (f < Fd) ? fm[f] * 0.5f : -3.0e38f;
  }
  float m = fmaxf(fmaxf(fmaxf(y[0], y[1]), fmaxf(y[2], y[3])), y[4]);
  m = wave_max(m);
#pragma unroll
  for (int j = 0; j < 5; ++j) y[j] -= m;

  // solve sum clip(y - tau, 0)^2 = 1; tau in [-1,0], decreasing in tau
  float lo = -1.f, hi = 0.f;
  for (int it = 0; it < 24; ++it) {
    float tau = 0.5f * (lo + hi);
    float ss = 0.f;
#pragma unroll
    for (int j = 0; j < 5; ++j) {
      float v = fmaxf(y[j] - tau, 0.f);
      ss = __builtin_fmaf(v, v, ss);
    }
    ss = wave_sum(ss);
    if (ss >= 1.f) lo = tau; else hi = tau;
  }
  float tau = 0.5f * (lo + hi);

  float* mo = a.out_masks + maskOff[d] + (size_t)s * Fd;
  const float* cp = a.cp[d] + (size_t)s * Fd * 2;
  const float* lr = a.lr[d] + (size_t)s * Fd * 2;
  float4* cpr = a.cprm + prmOff[d] + (size_t)s * Fd;
  int exB = exBase[d];
  float sum0 = 0.f, sum1 = 0.f;
  int base = 0;
#pragma unroll
  for (int j = 0; j < 5; ++j) {
    int f = lane + 64 * j;
    bool in = (f < Fd);
    float v = fmaxf(y[j] - tau, 0.f);
    float mk = v * v;
    float c10 = 0.f, ml0 = 0.f, ml1 = 0.f;
    if (in) {
      mo[f] = mk;
      float c0 = cp[2 * f], c1 = cp[2 * f + 1];
      ml0 = lr[2 * f] * mk;
      ml1 = lr[2 * f + 1] * mk;
      c10 = c1 - c0;
      sum0 += ml0;
      sum1 += ml1;
    }
    bool act = in && (v > 0.f);
    unsigned long long bm = __ballot(act);
    int pre = __popcll(bm & ((1ull << lane) - 1ull));
    if (act) {
      int fidx = (f < 256) ? f : (exB + f - 256);
      cpr[base + pre] =
          make_float4(c10, ml0 * 0.125f, ml1 * 0.125f, __int_as_float(fidx));
    }
    base += __popcll(bm);
  }
  sum0 = wave_sum(sum0);
  sum1 = wave_sum(sum1);
  if (lane == 0) {
    a.cstf[2 * (cstOff[d] + s)] = 0.5f * sum0;
    a.cstf[2 * (cstOff[d] + s) + 1] = 0.5f * sum1;
    a.cnt[cstOff[d] + s] = base;
  }
}

// 2-elem entmax15 closed form (scaled): t = c10 - x; tc = clamp(t,-2,2);
// e' = tc*sqrt(8 - tc^2) = 8*e. The 1/8 is folded into ml at build time.
__device__ __forceinline__ float entpair(float c10, float xv) {
  float t = c10 - xv;
  float tc = __builtin_amdgcn_fmed3f(t, -2.f, 2.f);
  float u = __builtin_fmaf(tc, -tc, 8.0f);
  return tc * __builtin_amdgcn_sqrtf(u);
}

// ---------------- one level inside the unified kernel ----------------
// 512 thr = 16 groups x 32 lanes(cols). SPG = 16/N groups per stump split the
// stump's compacted list; partials combine via pbuf; outputs -> xls rows
// [outRow, outRow+2N) (swizzled), becoming next level's "extra features".
template <int N, int FD>
__device__ __forceinline__ void ndt_level(const float4* __restrict__ cp,
                                          const int* __restrict__ cN,
                                          const float* __restrict__ cs,
                                          int outRow, int g, int l, int tid,
                                          float* __restrict__ xls,
                                          float (*__restrict__ pbuf)[2][32]) {
  constexpr int SPG = 16 / N;
  int s = g / SPG, slice = g - s * SPG;
  int nc = cN[s];
  const float4* ps = cp + (size_t)s * FD;
  float a0 = 0.f, a1 = 0.f;
  int jlo = slice * nc / SPG, jhi = (slice + 1) * nc / SPG;
#pragma unroll 4
  for (int j = jlo; j < jhi; ++j) {
    float4 p = ps[j];
    int row = __float_as_int(p.w);
    float xv = xls[row * 32 + (l ^ (row & 31))];
    float e = entpair(p.x, xv);
    a0 = __builtin_fmaf(e, p.y, a0);
    a1 = __builtin_fmaf(-e, p.z, a1);
  }
  pbuf[g][0][l] = a0;
  pbuf[g][1][l] = a1;
  __syncthreads();
  for (int o = tid >> 5; o < 2 * N; o += 16) {
    int s2 = o >> 1, par = o & 1;
    float v = cs[o];
#pragma unroll
    for (int k = 0; k < SPG; ++k) v += pbuf[s2 * SPG + k][par][l];
    int R = outRow + o;
    xls[R * 32 + (l ^ (R & 31))] = v;
  }
  __syncthreads();
}

// ---------------- unified kernel: all 6 levels, 32 cols per block ----------------
__global__ __launch_bounds__(512) void ndt_all(const float* __restrict__ x,
                                               const float4* __restrict__ cprm,
                                               const int* __restrict__ cnt,
                                               const float* __restrict__ cstf,
                                               float* __restrict__ out) {
  __shared__ float xls[318 * 32];
  __shared__ float pbuf[16][2][32];
  __shared__ float fres[64][33];
  int tid = threadIdx.x;
  int g = tid >> 5, l = tid & 31;
  int b0 = blockIdx.x * 32;
  // stage x rows (cols b0..b0+31): x[(b0+c)*256+f] -> xls[f*32 + (c ^ (f&31))]
  {
    int c = tid >> 4, seg = tid & 15;
    const float4* xp = (const float4*)(x + (size_t)(b0 + c) * 256 + seg * 16);
#pragma unroll
    for (int q = 0; q < 4; ++q) {
      float4 v = xp[q];
      int f = seg * 16 + 4 * q;
      xls[(f + 0) * 32 + (c ^ ((f + 0) & 31))] = v.x;
      xls[(f + 1) * 32 + (c ^ ((f + 1) & 31))] = v.y;
      xls[(f + 2) * 32 + (c ^ ((f + 2) & 31))] = v.z;
      xls[(f + 3) * 32 + (c ^ ((f + 3) & 31))] = v.w;
    }
  }
  __syncthreads();
  ndt_level<1, 256>(cprm, cnt, cstf, 256, g, l, tid, xls, pbuf);
  ndt_level<2, 258>(cprm + 256, cnt + 1, cstf + 2, 258, g, l, tid, xls, pbuf);
  ndt_level<4, 260>(cprm + 772, cnt + 3, cstf + 6, 262, g, l, tid, xls, pbuf);
  ndt_level<8, 264>(cprm + 1812, cnt + 7, cstf + 14, 270, g, l, tid, xls, pbuf);
  ndt_level<16, 272>(cprm + 3924, cnt + 15, cstf + 30, 286, g, l, tid, xls, pbuf);
  // level 5: 32 stumps, each group handles 2 sequentially, direct to fres
  {
    const float4* cp5 = cprm + 8276;
    const int* cN5 = cnt + 31;
    const float* cs5 = cstf + 62;
#pragma unroll
    for (int k = 0; k < 2; ++k) {
      int s = 2 * g + k;
      int nc = cN5[s];
      const float4* ps = cp5 + (size_t)s * 288;
      float a0 = cs5[2 * s], a1 = cs5[2 * s + 1];
#pragma unroll 4
      for (int j = 0; j < nc; ++j) {
        float4 p = ps[j];
        int row = __float_as_int(p.w);
        float xv = xls[row * 32 + (l ^ (row & 31))];
        float e = entpair(p.x, xv);
        a0 = __builtin_fmaf(e, p.y, a0);
        a1 = __builtin_fmaf(-e, p.z, a1);
      }
      fres[2 * s][l] = a0;
      fres[2 * s + 1][l] = a1;
    }
  }
  __syncthreads();
  // coalesced final write: col c's 64 outputs are contiguous in out
  {
    int c = tid >> 4, o = (tid & 15) * 4;
    float4 v = make_float4(fres[o][c], fres[o + 1][c], fres[o + 2][c],
                           fres[o + 3][c]);
    *(float4*)(out + (size_t)(b0 + c) * 64 + o) = v;
  }
}

extern "C" void kernel_launch(void* const* d_in, const int* in_sizes, int n_in,
                              void* d_out, int out_size, void* d_ws, size_t ws_size,
                              hipStream_t stream) {
  const float* x = (const float*)d_in[0];
  float* out = (float*)d_out;
  float* wsf = (float*)d_ws;

  // ws layout (float offsets)
  float4* cprm = (float4*)(wsf + 2575872);  // 17492 float4 (compacted)
  float* cstf = wsf + 2645840;              // 126 floats
  int* cnt = (int*)(wsf + 2645966);         // 63 ints

  MaskArgs ma;
  for (int d = 0; d < 6; ++d) {
    ma.fm[d] = (const float*)d_in[1 + 3 * d];
    ma.cp[d] = (const float*)d_in[2 + 3 * d];
    ma.lr[d] = (const float*)d_in[3 + 3 * d];
  }
  ma.out_masks = out;
  ma.cprm = cprm;
  ma.cnt = cnt;
  ma.cstf = cstf;
  hipLaunchKernelGGL(ndt_masks, dim3(63), dim3(64), 0, stream, ma);

  // all 6 levels in one kernel: 256 blocks x 512 thr, 32 cols/block
  hipLaunchKernelGGL(ndt_all, dim3(B_SZ / 32), dim3(512), 0, stream,
                     x, cprm, cnt, cstf, out);
}

// Round 17
// 45.535 us; speedup vs baseline: 1.2568x; 1.2568x over previous
//
#include <hip/hip_runtime.h>

#define B_SZ 8192

// xls row map (per 16-col block): 0-255 x; 256-257 out0; 258-261 out1;
// 262-269 out2; 270-285 out3; 286-317 out4.  Stride 17 (bank spread).

// ---------------- masks + unified COMPACTED params ----------
struct MaskArgs {
  const float* fm[6];
  const float* cp[6];
  const float* lr[6];
  float* out_masks;  // d_out base
  float4* cprm;      // compacted params {c10, ml0/8, ml1/8, fidx(xls row)}
  int* cnt;          // active count per stump (global stump idx)
  float* cstf;       // per-output 0.5*sum(ml)
};

__device__ __forceinline__ float wave_max(float v) {
#pragma unroll
  for (int o = 32; o > 0; o >>= 1) v = fmaxf(v, __shfl_xor(v, o));
  return v;
}
__device__ __forceinline__ float wave_sum(float v) {
#pragma unroll
  for (int o = 32; o > 0; o >>= 1) v += __shfl_xor(v, o);
  return v;
}

__global__ __launch_bounds__(64) void ndt_masks(MaskArgs a) {
  const int maskOff[6] = {524288, 524544, 525060, 526100, 528212, 532564};
  const int prmOff[6]  = {0, 256, 772, 1812, 3924, 8276};
  const int cstOff[6]  = {0, 1, 3, 7, 15, 31};
  const int exBase[6]  = {0, 256, 258, 262, 270, 286};  // xls row of extra f=256
  int bid = blockIdx.x, lane = threadIdx.x;
  int d = 0, s = bid, n = 1;
  while (s >= n) { s -= n; n <<= 1; ++d; }   // level d, stump s, n = 2^d
  int Fd = 256 + ((d > 0) ? n : 0);

  const float* fm = a.fm[d] + (size_t)s * Fd;
  float y[5];
#pragma unroll
  for (int j = 0; j < 5; ++j) {
    int f = lane + 64 * j;
    y[j] = (f < Fd) ? fm[f] * 0.5f : -3.0e38f;
  }
  float m = fmaxf(fmaxf(fmaxf(y[0], y[1]), fmaxf(y[2], y[3])), y[4]);
  m = wave_max(m);
#pragma unroll
  for (int j = 0; j < 5; ++j) y[j] -= m;

  // solve sum clip(y - tau, 0)^2 = 1; tau in [-1,0], decreasing in tau
  float lo = -1.f, hi = 0.f;
  for (int it = 0; it < 24; ++it) {
    float tau = 0.5f * (lo + hi);
    float ss = 0.f;
#pragma unroll
    for (int j = 0; j < 5; ++j) {
      float v = fmaxf(y[j] - tau, 0.f);
      ss = __builtin_fmaf(v, v, ss);
    }
    ss = wave_sum(ss);
    if (ss >= 1.f) lo = tau; else hi = tau;
  }
  float tau = 0.5f * (lo + hi);

  float* mo = a.out_masks + maskOff[d] + (size_t)s * Fd;
  const float* cp = a.cp[d] + (size_t)s * Fd * 2;
  const float* lr = a.lr[d] + (size_t)s * Fd * 2;
  float4* cpr = a.cprm + prmOff[d] + (size_t)s * Fd;
  int exB = exBase[d];
  float sum0 = 0.f, sum1 = 0.f;
  int base = 0;
#pragma unroll
  for (int j = 0; j < 5; ++j) {
    int f = lane + 64 * j;
    bool in = (f < Fd);
    float v = fmaxf(y[j] - tau, 0.f);
    float mk = v * v;
    float c10 = 0.f, ml0 = 0.f, ml1 = 0.f;
    if (in) {
      mo[f] = mk;
      float c0 = cp[2 * f], c1 = cp[2 * f + 1];
      ml0 = lr[2 * f] * mk;
      ml1 = lr[2 * f + 1] * mk;
      c10 = c1 - c0;
      sum0 += ml0;
      sum1 += ml1;
    }
    bool act = in && (v > 0.f);
    unsigned long long bm = __ballot(act);
    int pre = __popcll(bm & ((1ull << lane) - 1ull));
    if (act) {
      int fidx = (f < 256) ? f : (exB + f - 256);
      cpr[base + pre] =
          make_float4(c10, ml0 * 0.125f, ml1 * 0.125f, __int_as_float(fidx));
    }
    base += __popcll(bm);
  }
  sum0 = wave_sum(sum0);
  sum1 = wave_sum(sum1);
  if (lane == 0) {
    a.cstf[2 * (cstOff[d] + s)] = 0.5f * sum0;
    a.cstf[2 * (cstOff[d] + s) + 1] = 0.5f * sum1;
    a.cnt[cstOff[d] + s] = base;
  }
}

// 2-elem entmax15 closed form (scaled): t = c10 - x; tc = clamp(t,-2,2);
// e' = tc*sqrt(8 - tc^2) = 8*e. The 1/8 is folded into ml at build time.
__device__ __forceinline__ float entpair(float c10, float xv) {
  float t = c10 - xv;
  float tc = __builtin_amdgcn_fmed3f(t, -2.f, 2.f);
  float u = __builtin_fmaf(tc, -tc, 8.0f);
  return tc * __builtin_amdgcn_sqrtf(u);
}

// ---------------- one level inside the unified kernel ----------------
// 512 thr = 32 groups x 16 lanes(cols). SPG = 32/N groups per stump split the
// stump's compacted list; partials combine via pbuf; outputs -> xls rows
// [outRow, outRow+2N) (stride 17), becoming next level's "extra features".
template <int N, int FD>
__device__ __forceinline__ void ndt_level(const float4* __restrict__ cp,
                                          const int* __restrict__ cN,
                                          const float* __restrict__ cs,
                                          int outRow, int g, int l,
                                          float* __restrict__ xls,
                                          float (*__restrict__ pbuf)[2][16]) {
  constexpr int SPG = 32 / N;
  int s = g / SPG, slice = g - s * SPG;
  int nc = cN[s];
  const float4* ps = cp + (size_t)s * FD;
  float a0 = 0.f, a1 = 0.f;
  int jlo = slice * nc / SPG, jhi = (slice + 1) * nc / SPG;
#pragma unroll 4
  for (int j = jlo; j < jhi; ++j) {
    float4 p = ps[j];
    int row = __float_as_int(p.w);
    float xv = xls[row * 17 + l];
    float e = entpair(p.x, xv);
    a0 = __builtin_fmaf(e, p.y, a0);
    a1 = __builtin_fmaf(-e, p.z, a1);
  }
  pbuf[g][0][l] = a0;
  pbuf[g][1][l] = a1;
  __syncthreads();
  for (int o = g; o < 2 * N; o += 32) {
    int s2 = o >> 1, par = o & 1;
    float v = cs[o];
#pragma unroll
    for (int k = 0; k < SPG; ++k) v += pbuf[s2 * SPG + k][par][l];
    xls[(outRow + o) * 17 + l] = v;
  }
  __syncthreads();
}

// ---------------- unified kernel: all 6 levels, 16 cols per block ----------------
__global__ __launch_bounds__(512) void ndt_all(const float* __restrict__ x,
                                               const float4* __restrict__ cprm,
                                               const int* __restrict__ cnt,
                                               const float* __restrict__ cstf,
                                               float* __restrict__ out) {
  __shared__ float xls[318 * 17];
  __shared__ float pbuf[32][2][16];
  __shared__ float fres[64 * 17];
  int tid = threadIdx.x;
  int g = tid >> 4, l = tid & 15;
  int b0 = blockIdx.x * 16;
  // stage x (cols b0..b0+15): coalesced 8 floats/thread -> xls[f*17 + c]
  {
    int c = tid >> 5, seg = tid & 31;
    const float4* xp = (const float4*)(x + (size_t)(b0 + c) * 256 + seg * 8);
    float4 v0 = xp[0], v1 = xp[1];
    int f = seg * 8;
    xls[(f + 0) * 17 + c] = v0.x;
    xls[(f + 1) * 17 + c] = v0.y;
    xls[(f + 2) * 17 + c] = v0.z;
    xls[(f + 3) * 17 + c] = v0.w;
    xls[(f + 4) * 17 + c] = v1.x;
    xls[(f + 5) * 17 + c] = v1.y;
    xls[(f + 6) * 17 + c] = v1.z;
    xls[(f + 7) * 17 + c] = v1.w;
  }
  __syncthreads();
  ndt_level<1, 256>(cprm, cnt, cstf, 256, g, l, xls, pbuf);
  ndt_level<2, 258>(cprm + 256, cnt + 1, cstf + 2, 258, g, l, xls, pbuf);
  ndt_level<4, 260>(cprm + 772, cnt + 3, cstf + 6, 262, g, l, xls, pbuf);
  ndt_level<8, 264>(cprm + 1812, cnt + 7, cstf + 14, 270, g, l, xls, pbuf);
  ndt_level<16, 272>(cprm + 3924, cnt + 15, cstf + 30, 286, g, l, xls, pbuf);
  // level 5: 32 stumps, one per group, direct to fres
  {
    const float4* cp5 = cprm + 8276;
    int nc = cnt[31 + g];
    const float4* ps = cp5 + (size_t)g * 288;
    float a0 = cstf[62 + 2 * g], a1 = cstf[62 + 2 * g + 1];
#pragma unroll 4
    for (int j = 0; j < nc; ++j) {
      float4 p = ps[j];
      int row = __float_as_int(p.w);
      float xv = xls[row * 17 + l];
      float e = entpair(p.x, xv);
      a0 = __builtin_fmaf(e, p.y, a0);
      a1 = __builtin_fmaf(-e, p.z, a1);
    }
    fres[(2 * g) * 17 + l] = a0;
    fres[(2 * g + 1) * 17 + l] = a1;
  }
  __syncthreads();
  // coalesced final write: col c's 64 outputs contiguous in out
  {
    int c = tid >> 5, o = (tid & 31) * 2;
    float2 v = make_float2(fres[o * 17 + c], fres[(o + 1) * 17 + c]);
    *(float2*)(out + (size_t)(b0 + c) * 64 + o) = v;
  }
}

extern "C" void kernel_launch(void* const* d_in, const int* in_sizes, int n_in,
                              void* d_out, int out_size, void* d_ws, size_t ws_size,
                              hipStream_t stream) {
  const float* x = (const float*)d_in[0];
  float* out = (float*)d_out;
  float* wsf = (float*)d_ws;

  // ws layout (float offsets)
  float4* cprm = (float4*)(wsf + 2575872);  // 17492 float4 (compacted)
  float* cstf = wsf + 2645840;              // 126 floats
  int* cnt = (int*)(wsf + 2645966);         // 63 ints

  MaskArgs ma;
  for (int d = 0; d < 6; ++d) {
    ma.fm[d] = (const float*)d_in[1 + 3 * d];
    ma.cp[d] = (const float*)d_in[2 + 3 * d];
    ma.lr[d] = (const float*)d_in[3 + 3 * d];
  }
  ma.out_masks = out;
  ma.cprm = cprm;
  ma.cnt = cnt;
  ma.cstf = cstf;
  hipLaunchKernelGGL(ndt_masks, dim3(63), dim3(64), 0, stream, ma);

  // all 6 levels in one kernel: 512 blocks x 512 thr, 16 cols/block
  hipLaunchKernelGGL(ndt_all, dim3(B_SZ / 16), dim3(512), 0, stream,
                     x, cprm, cnt, cstf, out);
}

// Round 18
// 44.178 us; speedup vs baseline: 1.2954x; 1.0307x over previous
//
#include <hip/hip_runtime.h>

#define B_SZ 8192

// xls row map (per 8-col block, stride 9): 0-255 x; 256-257 out0; 258-261 out1;
// 262-269 out2; 270-285 out3; 286-317 out4; 318-381 out5 (final).

// ---------------- masks + unified COMPACTED params ----------
struct MaskArgs {
  const float* fm[6];
  const float* cp[6];
  const float* lr[6];
  float* out_masks;  // d_out base
  float4* cprm;      // compacted params {c10, ml0/8, ml1/8, fidx(xls row)}
  int* cnt;          // active count per stump (global stump idx)
  float* cstf;       // per-output 0.5*sum(ml)
};

__device__ __forceinline__ float wave_max(float v) {
#pragma unroll
  for (int o = 32; o > 0; o >>= 1) v = fmaxf(v, __shfl_xor(v, o));
  return v;
}
__device__ __forceinline__ float wave_sum(float v) {
#pragma unroll
  for (int o = 32; o > 0; o >>= 1) v += __shfl_xor(v, o);
  return v;
}

__global__ __launch_bounds__(64) void ndt_masks(MaskArgs a) {
  const int maskOff[6] = {524288, 524544, 525060, 526100, 528212, 532564};
  const int prmOff[6]  = {0, 256, 772, 1812, 3924, 8276};
  const int cstOff[6]  = {0, 1, 3, 7, 15, 31};
  const int exBase[6]  = {0, 256, 258, 262, 270, 286};  // xls row of extra f=256
  int bid = blockIdx.x, lane = threadIdx.x;
  int d = 0, s = bid, n = 1;
  while (s >= n) { s -= n; n <<= 1; ++d; }   // level d, stump s, n = 2^d
  int Fd = 256 + ((d > 0) ? n : 0);

  const float* fm = a.fm[d] + (size_t)s * Fd;
  float y[5];
#pragma unroll
  for (int j = 0; j < 5; ++j) {
    int f = lane + 64 * j;
    y[j] = (f < Fd) ? fm[f] * 0.5f : -3.0e38f;
  }
  float m = fmaxf(fmaxf(fmaxf(y[0], y[1]), fmaxf(y[2], y[3])), y[4]);
  m = wave_max(m);
#pragma unroll
  for (int j = 0; j < 5; ++j) y[j] -= m;

  // solve sum clip(y - tau, 0)^2 = 1; tau in [-1,0], decreasing in tau
  float lo = -1.f, hi = 0.f;
  for (int it = 0; it < 24; ++it) {
    float tau = 0.5f * (lo + hi);
    float ss = 0.f;
#pragma unroll
    for (int j = 0; j < 5; ++j) {
      float v = fmaxf(y[j] - tau, 0.f);
      ss = __builtin_fmaf(v, v, ss);
    }
    ss = wave_sum(ss);
    if (ss >= 1.f) lo = tau; else hi = tau;
  }
  float tau = 0.5f * (lo + hi);

  float* mo = a.out_masks + maskOff[d] + (size_t)s * Fd;
  const float* cp = a.cp[d] + (size_t)s * Fd * 2;
  const float* lr = a.lr[d] + (size_t)s * Fd * 2;
  float4* cpr = a.cprm + prmOff[d] + (size_t)s * Fd;
  int exB = exBase[d];
  float sum0 = 0.f, sum1 = 0.f;
  int base = 0;
#pragma unroll
  for (int j = 0; j < 5; ++j) {
    int f = lane + 64 * j;
    bool in = (f < Fd);
    float v = fmaxf(y[j] - tau, 0.f);
    float mk = v * v;
    float c10 = 0.f, ml0 = 0.f, ml1 = 0.f;
    if (in) {
      mo[f] = mk;
      float c0 = cp[2 * f], c1 = cp[2 * f + 1];
      ml0 = lr[2 * f] * mk;
      ml1 = lr[2 * f + 1] * mk;
      c10 = c1 - c0;
      sum0 += ml0;
      sum1 += ml1;
    }
    bool act = in && (v > 0.f);
    unsigned long long bm = __ballot(act);
    int pre = __popcll(bm & ((1ull << lane) - 1ull));
    if (act) {
      int fidx = (f < 256) ? f : (exB + f - 256);
      cpr[base + pre] =
          make_float4(c10, ml0 * 0.125f, ml1 * 0.125f, __int_as_float(fidx));
    }
    base += __popcll(bm);
  }
  sum0 = wave_sum(sum0);
  sum1 = wave_sum(sum1);
  if (lane == 0) {
    a.cstf[2 * (cstOff[d] + s)] = 0.5f * sum0;
    a.cstf[2 * (cstOff[d] + s) + 1] = 0.5f * sum1;
    a.cnt[cstOff[d] + s] = base;
  }
}

// 2-elem entmax15 closed form (scaled): t = c10 - x; tc = clamp(t,-2,2);
// e' = tc*sqrt(8 - tc^2) = 8*e. The 1/8 is folded into ml at build time.
__device__ __forceinline__ float entpair(float c10, float xv) {
  float t = c10 - xv;
  float tc = __builtin_amdgcn_fmed3f(t, -2.f, 2.f);
  float u = __builtin_fmaf(tc, -tc, 8.0f);
  return tc * __builtin_amdgcn_sqrtf(u);
}

// ---------------- one level inside the unified kernel ----------------
// 512 thr = 64 groups x 8 lanes(cols). SPG = 64/N groups per stump split the
// stump's compacted list; partials combine via pbuf; outputs -> xls rows
// [outRow, outRow+2N) (stride 9), becoming next level's "extra features".
template <int N, int FD>
__device__ __forceinline__ void ndt_level(const float4* __restrict__ cp,
                                          const int* __restrict__ cN,
                                          const float* __restrict__ cs,
                                          int outRow, int g, int l,
                                          float* __restrict__ xls,
                                          float (*__restrict__ pbuf)[2][8]) {
  constexpr int SPG = 64 / N;
  int s = g / SPG, slice = g - s * SPG;
  int nc = cN[s];
  const float4* ps = cp + (size_t)s * FD;
  float a0 = 0.f, a1 = 0.f;
  int jlo = slice * nc / SPG, jhi = (slice + 1) * nc / SPG;
#pragma unroll 4
  for (int j = jlo; j < jhi; ++j) {
    float4 p = ps[j];
    int row = __float_as_int(p.w);
    float xv = xls[row * 9 + l];
    float e = entpair(p.x, xv);
    a0 = __builtin_fmaf(e, p.y, a0);
    a1 = __builtin_fmaf(-e, p.z, a1);
  }
  pbuf[g][0][l] = a0;
  pbuf[g][1][l] = a1;
  __syncthreads();
  for (int o = g; o < 2 * N; o += 64) {
    int s2 = o >> 1, par = o & 1;
    float v = cs[o];
#pragma unroll
    for (int k = 0; k < SPG; ++k) v += pbuf[s2 * SPG + k][par][l];
    xls[(outRow + o) * 9 + l] = v;
  }
  __syncthreads();
}

// ---------------- unified kernel: all 6 levels, 8 cols per block ----------------
__global__ __launch_bounds__(512, 8) void ndt_all(const float* __restrict__ x,
                                                  const float4* __restrict__ cprm,
                                                  const int* __restrict__ cnt,
                                                  const float* __restrict__ cstf,
                                                  float* __restrict__ out) {
  __shared__ float xls[382 * 9];
  __shared__ float pbuf[64][2][8];
  int tid = threadIdx.x;
  int g = tid >> 3, l = tid & 7;
  int b0 = blockIdx.x * 8;
  // stage x (cols b0..b0+7): 64 thr/col, float4 each -> xls[f*9 + c]
  {
    int c = tid >> 6, seg = tid & 63;
    float4 v = *(const float4*)(x + (size_t)(b0 + c) * 256 + seg * 4);
    int f = seg * 4;
    xls[(f + 0) * 9 + c] = v.x;
    xls[(f + 1) * 9 + c] = v.y;
    xls[(f + 2) * 9 + c] = v.z;
    xls[(f + 3) * 9 + c] = v.w;
  }
  __syncthreads();
  ndt_level<1, 256>(cprm, cnt, cstf, 256, g, l, xls, pbuf);
  ndt_level<2, 258>(cprm + 256, cnt + 1, cstf + 2, 258, g, l, xls, pbuf);
  ndt_level<4, 260>(cprm + 772, cnt + 3, cstf + 6, 262, g, l, xls, pbuf);
  ndt_level<8, 264>(cprm + 1812, cnt + 7, cstf + 14, 270, g, l, xls, pbuf);
  ndt_level<16, 272>(cprm + 3924, cnt + 15, cstf + 30, 286, g, l, xls, pbuf);
  ndt_level<32, 288>(cprm + 8276, cnt + 31, cstf + 62, 318, g, l, xls, pbuf);
  // coalesced final write: col c's 64 outputs contiguous in out
  {
    int c = tid >> 6, o = tid & 63;
    out[(size_t)(b0 + c) * 64 + o] = xls[(318 + o) * 9 + c];
  }
}

extern "C" void kernel_launch(void* const* d_in, const int* in_sizes, int n_in,
                              void* d_out, int out_size, void* d_ws, size_t ws_size,
                              hipStream_t stream) {
  const float* x = (const float*)d_in[0];
  float* out = (float*)d_out;
  float* wsf = (float*)d_ws;

  // ws layout (float offsets)
  float4* cprm = (float4*)(wsf + 2575872);  // 17492 float4 (compacted)
  float* cstf = wsf + 2645840;              // 126 floats
  int* cnt = (int*)(wsf + 2645966);         // 63 ints

  MaskArgs ma;
  for (int d = 0; d < 6; ++d) {
    ma.fm[d] = (const float*)d_in[1 + 3 * d];
    ma.cp[d] = (const float*)d_in[2 + 3 * d];
    ma.lr[d] = (const float*)d_in[3 + 3 * d];
  }
  ma.out_masks = out;
  ma.cprm = cprm;
  ma.cnt = cnt;
  ma.cstf = cstf;
  hipLaunchKernelGGL(ndt_masks, dim3(63), dim3(64), 0, stream, ma);

  // all 6 levels in one kernel: 1024 blocks x 512 thr, 8 cols/block
  hipLaunchKernelGGL(ndt_all, dim3(B_SZ / 8), dim3(512), 0, stream,
                     x, cprm, cnt, cstf, out);
}